// Round 4
// baseline (396.613 us; speedup 1.0000x reference)
//
#include <hip/hip_runtime.h>
#include <math.h>

#define D 128
#define NCLS 40
#define NBLK_P1 256      // partition blocks; bucket = 128 nodes, nbuk <= 1024
#define FM 64            // fused aggregate+GEMM M-tile

typedef unsigned int u32;
typedef __attribute__((ext_vector_type(8))) short short8;
typedef __attribute__((ext_vector_type(4))) float f32x4;

__device__ inline float bflo(u32 u){ return __uint_as_float(u << 16); }
__device__ inline float bfhi(u32 u){ return __uint_as_float(u & 0xffff0000u); }
__device__ inline u32 pack2bf(float a, float b){
  u32 ua = __float_as_uint(a), ub = __float_as_uint(b);
  ua += 0x7fffu + ((ua >> 16) & 1u);
  ub += 0x7fffu + ((ub >> 16) & 1u);
  return (ua >> 16) | (ub & 0xffff0000u);
}
__device__ inline unsigned short pack1bf(float a){
  u32 ua = __float_as_uint(a);
  ua += 0x7fffu + ((ua >> 16) & 1u);
  return (unsigned short)(ua >> 16);
}

// ---------------- fused prep: x->bf16 + weight converts + partition histogram ----------------
// block ranges: [0,nbX) f2bf | 128 Wt1/Wt2 | 32 Wt3b+bias3b | NBLK_P1 hist
__global__ __launch_bounds__(256) void prep_k(
    const float4* __restrict__ x4, uint2* __restrict__ xb, int n4,
    const float* __restrict__ W1l, const float* __restrict__ W1r, u32* __restrict__ Wt1,
    const float* __restrict__ W2l, const float* __restrict__ W2r, u32* __restrict__ Wt2,
    const float* __restrict__ W3l, const float* __restrict__ W3r,
    u32* __restrict__ Wt3b, float* __restrict__ bias3b, const float* __restrict__ b3,
    const int* __restrict__ dst, int* __restrict__ gcnt, int E, int nbuk, int nbX)
{
  __shared__ int cnt[1024];
  const int b = blockIdx.x;
  const int tid = threadIdx.x;
  if (b < nbX){
    int i = b * 256 + tid;
    if (i < n4){
      float4 v = x4[i];
      xb[i] = make_uint2(pack2bf(v.x, v.y), pack2bf(v.z, v.w));
    }
  } else if (b < nbX + 128){
    const bool first = (b < nbX + 64);
    const float* Wl = first ? W1l : W2l;
    const float* Wr = first ? W1r : W2r;
    u32* Wt = first ? Wt1 : Wt2;
    int i = ((b - nbX) & 63) * 256 + tid;         // 0..16383
    int nn = i >> 7, kp = i & 127;
    int k = kp * 2;
    float a, c;
    if (k < 128){ a = Wl[(size_t)k * 128 + nn]; c = Wl[(size_t)(k + 1) * 128 + nn]; }
    else        { a = Wr[(size_t)(k - 128) * 128 + nn]; c = Wr[(size_t)(k - 127) * 128 + nn]; }
    Wt[(size_t)nn * 128 + kp] = pack2bf(a, c);
  } else if (b < nbX + 160){
    // Wt3b[128 out][64 u32 k], K=128: out 0..39 = W3l^T, 64..103 = W3r^T, else 0
    int i = (b - nbX - 128) * 256 + tid;          // 0..8191
    if (i < 128 * 64){
      int nn = i >> 6, kp = i & 63;
      int k = kp * 2;
      float a = 0.f, c = 0.f;
      if (nn < NCLS){
        a = W3l[(size_t)k * NCLS + nn]; c = W3l[(size_t)(k + 1) * NCLS + nn];
      } else if (nn >= 64 && nn < 64 + NCLS){
        int cc = nn - 64;
        a = W3r[(size_t)k * NCLS + cc]; c = W3r[(size_t)(k + 1) * NCLS + cc];
      }
      Wt3b[(size_t)nn * 64 + kp] = pack2bf(a, c);
    }
    if (b == nbX + 128 && tid < 128)
      bias3b[tid] = (tid >= 64 && tid < 64 + NCLS) ? b3[tid - 64] : 0.f;
  } else {
    // partition histogram (LDS only)
    const int hb = b - nbX - 160;                 // 0..NBLK_P1-1
    for (int i = tid; i < nbuk; i += 256) cnt[i] = 0;
    __syncthreads();
    const int per = (E + NBLK_P1 - 1) / NBLK_P1;
    const int e0 = hb * per;
    const int e1 = min(e0 + per, E);
    for (int i = e0 + tid; i < e1; i += 256)
      atomicAdd(&cnt[dst[i] >> 7], 1);
    __syncthreads();
    for (int i = tid; i < nbuk; i += 256)
      gcnt[(size_t)hb * nbuk + i] = cnt[i];
  }
}

// ---------------- CSR build: chain-free LDS radix partition ----------------
// parallel scan path: per-bucket totals -> 1-block scan -> per-bucket goff scan

__global__ __launch_bounds__(256) void bsum_k(
    const int* __restrict__ gcnt, int* __restrict__ btot, int nbuk)
{
  __shared__ int sm[256];
  const int j = blockIdx.x;
  sm[threadIdx.x] = gcnt[(size_t)threadIdx.x * nbuk + j];
  __syncthreads();
  for (int off = 128; off > 0; off >>= 1){
    if (threadIdx.x < off) sm[threadIdx.x] += sm[threadIdx.x + off];
    __syncthreads();
  }
  if (threadIdx.x == 0) btot[j] = sm[0];
}

__global__ __launch_bounds__(1024) void scan_k(
    const int* __restrict__ btot, int* __restrict__ bbase, int nbuk)
{
  __shared__ int sm[1024];
  const int j = threadIdx.x;
  int v = (j < nbuk) ? btot[j] : 0;
  sm[j] = v;
  __syncthreads();
  int acc = v;
  for (int off = 1; off < 1024; off <<= 1){
    int t = (j >= off) ? sm[j - off] : 0;
    __syncthreads();
    acc += t; sm[j] = acc;
    __syncthreads();
  }
  if (j < nbuk){
    bbase[j] = acc - v;                 // exclusive
    if (j == nbuk - 1) bbase[nbuk] = acc;
  }
}

__global__ __launch_bounds__(256) void goff_k(
    const int* __restrict__ gcnt, const int* __restrict__ bbase,
    int* __restrict__ goff, int nbuk)
{
  __shared__ int sm[256];
  const int j = blockIdx.x;
  const int i = threadIdx.x;
  int v = gcnt[(size_t)i * nbuk + j];
  sm[i] = v;
  __syncthreads();
  int acc = v;
  for (int off = 1; off < 256; off <<= 1){
    int t = (i >= off) ? sm[i - off] : 0;
    __syncthreads();
    acc += t; sm[i] = acc;
    __syncthreads();
  }
  goff[(size_t)i * nbuk + j] = bbase[j] + acc - v;   // exclusive within bucket
}

// P1b: scatter edges into bucket staging; entry = (src<<7)|dst_local (4B; needs src < 2^25)
__global__ __launch_bounds__(256) void part_fill_k(
    const int* __restrict__ src, const int* __restrict__ dst,
    const int* __restrict__ goff, u32* __restrict__ staging,
    int E, int nbuk)
{
  __shared__ int boff[1024];
  __shared__ int cur[1024];
  const int tid = threadIdx.x;
  for (int i = tid; i < nbuk; i += 256){
    boff[i] = goff[(size_t)blockIdx.x * nbuk + i];
    cur[i] = 0;
  }
  __syncthreads();
  const int per = (E + NBLK_P1 - 1) / NBLK_P1;
  const int e0 = blockIdx.x * per;
  const int e1 = min(e0 + per, E);
  for (int i = e0 + tid; i < e1; i += 256){
    int d = dst[i];
    int s = src[i];
    int b = d >> 7;
    int p = atomicAdd(&cur[b], 1);
    staging[boff[b] + p] = ((u32)s << 7) | (u32)(d & 127);
  }
}

// P2: one block per bucket. LDS degree histogram -> local scan -> csr_off/deg_inv,
// then ordered csr_src scatter confined to the bucket's ~contiguous window.
__global__ __launch_bounds__(256) void bucket_csr_k(
    const u32* __restrict__ staging, const int* __restrict__ bbase,
    int* __restrict__ csr_off, float* __restrict__ deg_inv,
    int* __restrict__ csr_src, int N)
{
  __shared__ int ldeg[128];
  __shared__ int sm[128];
  __shared__ int lbase[128];
  __shared__ int lpos[128];
  const int b = blockIdx.x;
  const int node0 = b << 7;
  const int tid = threadIdx.x;
  if (tid < 128) ldeg[tid] = 0;
  __syncthreads();
  const int lo = bbase[b], hi = bbase[b + 1];
  for (int i = lo + tid; i < hi; i += 256)
    atomicAdd(&ldeg[staging[i] & 127u], 1);
  __syncthreads();
  if (tid < 128) sm[tid] = ldeg[tid];
  __syncthreads();
  for (int off = 1; off < 128; off <<= 1){
    int t = (tid >= off && tid < 128) ? sm[tid - off] : 0;
    __syncthreads();
    if (tid < 128) sm[tid] += t;
    __syncthreads();
  }
  if (tid < 128){
    const int excl = sm[tid] - ldeg[tid];
    lbase[tid] = lo + excl;
    lpos[tid] = 0;
    const int node = node0 + tid;
    if (node < N){
      csr_off[node] = lo + excl;
      deg_inv[node] = 1.0f / fmaxf((float)ldeg[tid], 1.0f);
    } else if (node == N){
      csr_off[N] = lo + excl;
    }
  }
  if (tid == 0 && b == (int)gridDim.x - 1) csr_off[N] = hi;   // covers N%128==0
  __syncthreads();
  for (int i = lo + tid; i < hi; i += 256){
    u32 v = staging[i];
    int dloc = (int)(v & 127u);
    int p = atomicAdd(&lpos[dloc], 1);
    csr_src[lbase[dloc] + p] = (int)(v >> 7);
  }
}

// ---------------- helpers ----------------
__device__ inline void add8(float* acc, uint4 v){
  acc[0] += bflo(v.x); acc[1] += bfhi(v.x);
  acc[2] += bflo(v.y); acc[3] += bfhi(v.y);
  acc[4] += bflo(v.z); acc[5] += bfhi(v.z);
  acc[6] += bflo(v.w); acc[7] += bfhi(v.w);
}

// ---------------- fused: mean-aggregate 64 nodes + GEMM(relu([agg|x]@Wt^T+b)) ----------------
// Phase 1: 16 lanes/node gather (identical inner loop to the proven aggregate_k),
//          writing bf16 agg rows + the node's own row into As (K=256 per row).
// Phase 2: 64x128 MFMA GEMM from As/Bs; coalesced uint4 store via LDS repack.
// LDS = As 33KB + Bs 10KB = 43KB -> 3 blocks/CU; 1563 blocks -> ~2.03 waves (low tail).
__global__ __launch_bounds__(256) void fused_agg_gemm_k(
    const u32* __restrict__ feat, const int* __restrict__ coff,
    const int* __restrict__ csr_src, const float* __restrict__ deg_inv,
    const u32* __restrict__ Wt, const float* __restrict__ bias,
    u32* __restrict__ out, int n)
{
  __shared__ u32 As[FM * 132];     // 64 rows x 128 u32 payload, stride 132 (2-way banks)
  __shared__ u32 Bs[128 * 20];
  const int tid = threadIdx.x;
  const int row0 = blockIdx.x * FM;

  // ---- Phase 1: aggregate (cols 0..63 u32) ----
  {
    const int g = tid >> 4;
    const int lane = tid & 15;
    const uint4* __restrict__ f4 = (const uint4*)feat;
    for (int sp = 0; sp < 4; ++sp){
      const int r = sp * 16 + g;
      const int node = row0 + r;
      float acc[8] = {0.f,0.f,0.f,0.f,0.f,0.f,0.f,0.f};
      float di = 0.f;
      if (node < n){
        di = deg_inv[node];
        const int lo = coff[node], hi = coff[node + 1];
        int e = lo;
        for (; e + 7 < hi; e += 8){
          int s0 = csr_src[e],     s1 = csr_src[e + 1];
          int s2 = csr_src[e + 2], s3 = csr_src[e + 3];
          int s4 = csr_src[e + 4], s5 = csr_src[e + 5];
          int s6 = csr_src[e + 6], s7 = csr_src[e + 7];
          uint4 v0 = f4[(size_t)s0 * 16 + lane];
          uint4 v1 = f4[(size_t)s1 * 16 + lane];
          uint4 v2 = f4[(size_t)s2 * 16 + lane];
          uint4 v3 = f4[(size_t)s3 * 16 + lane];
          uint4 v4 = f4[(size_t)s4 * 16 + lane];
          uint4 v5 = f4[(size_t)s5 * 16 + lane];
          uint4 v6 = f4[(size_t)s6 * 16 + lane];
          uint4 v7 = f4[(size_t)s7 * 16 + lane];
          add8(acc, v0); add8(acc, v1); add8(acc, v2); add8(acc, v3);
          add8(acc, v4); add8(acc, v5); add8(acc, v6); add8(acc, v7);
        }
        for (; e + 3 < hi; e += 4){
          int s0 = csr_src[e],     s1 = csr_src[e + 1];
          int s2 = csr_src[e + 2], s3 = csr_src[e + 3];
          uint4 v0 = f4[(size_t)s0 * 16 + lane];
          uint4 v1 = f4[(size_t)s1 * 16 + lane];
          uint4 v2 = f4[(size_t)s2 * 16 + lane];
          uint4 v3 = f4[(size_t)s3 * 16 + lane];
          add8(acc, v0); add8(acc, v1); add8(acc, v2); add8(acc, v3);
        }
        for (; e < hi; ++e){
          uint4 v0 = f4[(size_t)csr_src[e] * 16 + lane];
          add8(acc, v0);
        }
      }
      uint4 o;
      o.x = pack2bf(acc[0] * di, acc[1] * di);
      o.y = pack2bf(acc[2] * di, acc[3] * di);
      o.z = pack2bf(acc[4] * di, acc[5] * di);
      o.w = pack2bf(acc[6] * di, acc[7] * di);
      *(uint4*)&As[r * 132 + lane * 4] = o;
    }
    // x-half (cols 64..127 u32): coalesced copy of the tile's own rows
    for (int i = tid; i < FM * 16; i += 256){
      int r = i >> 4, q = i & 15;
      int gr = row0 + r;
      uint4 v = make_uint4(0, 0, 0, 0);
      if (gr < n) v = *(const uint4*)(feat + (size_t)gr * 64 + q * 4);
      *(uint4*)&As[r * 132 + 64 + q * 4] = v;
    }
  }
  __syncthreads();

  // ---- Phase 2: GEMM 64x128, K=256 ----
  const int l = tid & 63, w = tid >> 6;
  const int lm = l & 15, lq = l >> 4;
  f32x4 acc2[8];
  #pragma unroll
  for (int ni = 0; ni < 8; ni++) acc2[ni] = (f32x4){0.f, 0.f, 0.f, 0.f};

  for (int kt = 0; kt < 8; ++kt){
    #pragma unroll
    for (int i = 0; i < 2; i++){
      int c2 = tid + 256 * i;
      int brow = c2 >> 2, q = c2 & 3;
      uint4 bv = *(const uint4*)(Wt + (size_t)brow * 128 + kt * 16 + q * 4);
      *(uint4*)&Bs[brow * 20 + q * 4] = bv;
    }
    __syncthreads();
    short8 af = *(const short8*)&As[(w * 16 + lm) * 132 + kt * 16 + lq * 4];
    #pragma unroll
    for (int ni = 0; ni < 8; ni++){
      short8 bf = *(const short8*)&Bs[(ni * 16 + lm) * 20 + lq * 4];
      acc2[ni] = __builtin_amdgcn_mfma_f32_16x16x32_bf16(af, bf, acc2[ni], 0, 0, 0);
    }
    __syncthreads();
  }

  // ---- epilogue: relu + bias, LDS repack (reuse As), coalesced uint4 store ----
  float bb[8];
  #pragma unroll
  for (int ni = 0; ni < 8; ni++) bb[ni] = bias[ni * 16 + lm];
  unsigned short* es = (unsigned short*)As + w * (16 * 136);
  #pragma unroll
  for (int r = 0; r < 4; r++){
    const int Lr = lq * 4 + r;
    #pragma unroll
    for (int ni = 0; ni < 8; ni++){
      float v = fmaxf(acc2[ni][r] + bb[ni], 0.f);
      es[Lr * 136 + ni * 16 + lm] = pack1bf(v);
    }
  }
  __syncthreads();
  uint4* outv = (uint4*)out;
  const int cl = l & 15;
  const int rsub = l >> 4;
  #pragma unroll
  for (int p = 0; p < 4; p++){
    const int Lr = p * 4 + rsub;
    const int row = row0 + w * 16 + Lr;
    uint4 t = *(const uint4*)&es[Lr * 136 + cl * 8];
    if (row < n) outv[(size_t)row * 16 + cl] = t;
  }
}

// ---------------- layer-3 pre-GEMM (K=128, no relu): yz = h @ Wt3b^T + bias3b ----------------
__global__ __launch_bounds__(256) void gemm3_mfma_k(
    const u32* __restrict__ A, const u32* __restrict__ Wt3b,
    const float* __restrict__ bias, u32* __restrict__ out, int n)
{
  __shared__ u32 smem[8704];
  u32* As_u = smem;
  u32* Bs_u = smem + 2560;
  const int tid = threadIdx.x;
  const int row0 = blockIdx.x * 128;
  const int l = tid & 63, w = tid >> 6;
  const int lm = l & 15, lq = l >> 4;

  f32x4 acc[2][8];
  #pragma unroll
  for (int mi = 0; mi < 2; mi++)
    #pragma unroll
    for (int ni = 0; ni < 8; ni++) acc[mi][ni] = (f32x4){0.f, 0.f, 0.f, 0.f};

  for (int kt = 0; kt < 4; ++kt){
    #pragma unroll
    for (int i = 0; i < 2; i++){
      int chunk = tid + 256 * i;
      int row = chunk >> 2, q = chunk & 3;
      uint4 av = make_uint4(0, 0, 0, 0);
      int gr = row0 + row;
      if (gr < n) av = *(const uint4*)(A + (size_t)gr * 64 + kt * 16 + q * 4);
      *(uint4*)&As_u[row * 20 + q * 4] = av;
      uint4 bv = *(const uint4*)(Wt3b + (size_t)row * 64 + kt * 16 + q * 4);
      *(uint4*)&Bs_u[row * 20 + q * 4] = bv;
    }
    __syncthreads();
    short8 af0 = *(const short8*)&As_u[(w * 32 + lm) * 20 + lq * 4];
    short8 af1 = *(const short8*)&As_u[(w * 32 + 16 + lm) * 20 + lq * 4];
    #pragma unroll
    for (int ni = 0; ni < 8; ni++){
      short8 bf = *(const short8*)&Bs_u[(ni * 16 + lm) * 20 + lq * 4];
      acc[0][ni] = __builtin_amdgcn_mfma_f32_16x16x32_bf16(af0, bf, acc[0][ni], 0, 0, 0);
      acc[1][ni] = __builtin_amdgcn_mfma_f32_16x16x32_bf16(af1, bf, acc[1][ni], 0, 0, 0);
    }
    __syncthreads();
  }

  float bb[8];
  #pragma unroll
  for (int ni = 0; ni < 8; ni++) bb[ni] = bias[ni * 16 + lm];
  unsigned short* es = (unsigned short*)smem + w * (32 * 136);
  #pragma unroll
  for (int mi = 0; mi < 2; mi++)
    #pragma unroll
    for (int r = 0; r < 4; r++){
      const int Lr = mi * 16 + lq * 4 + r;
      #pragma unroll
      for (int ni = 0; ni < 8; ni++){
        float v = acc[mi][ni][r] + bb[ni];
        es[Lr * 136 + ni * 16 + lm] = pack1bf(v);
      }
    }
  __syncthreads();
  uint4* outv = (uint4*)out;
  const int cl = l & 15;
  const int rsub = l >> 4;
  #pragma unroll
  for (int p = 0; p < 8; p++){
    const int Lr = p * 4 + rsub;
    const int row = row0 + w * 32 + Lr;
    uint4 t = *(const uint4*)&es[Lr * 136 + cl * 8];
    if (row < n) outv[(size_t)row * 16 + cl] = t;
  }
}

// ---------------- fused: out = log_softmax(mean-gather(y) + z), 8-way unrolled ----------------
__global__ __launch_bounds__(256) void agg_softmax_k(
    const u32* __restrict__ yz, const int* __restrict__ coff,
    const int* __restrict__ csr_src, const float* __restrict__ deg_inv,
    float* __restrict__ out, int n)
{
  const int g = threadIdx.x >> 3;
  const int lane = threadIdx.x & 7;
  const int node = blockIdx.x * 32 + g;
  if (node >= n) return;
  const int lo = coff[node], hi = coff[node + 1];
  const uint4* __restrict__ f4 = (const uint4*)yz;    // 16 uint4 per row; y = first 8
  float acc[8] = {0.f,0.f,0.f,0.f,0.f,0.f,0.f,0.f};
  int e = lo;
  for (; e + 7 < hi; e += 8){
    int s0 = csr_src[e],     s1 = csr_src[e + 1];
    int s2 = csr_src[e + 2], s3 = csr_src[e + 3];
    int s4 = csr_src[e + 4], s5 = csr_src[e + 5];
    int s6 = csr_src[e + 6], s7 = csr_src[e + 7];
    uint4 v0 = f4[(size_t)s0 * 16 + lane];
    uint4 v1 = f4[(size_t)s1 * 16 + lane];
    uint4 v2 = f4[(size_t)s2 * 16 + lane];
    uint4 v3 = f4[(size_t)s3 * 16 + lane];
    uint4 v4 = f4[(size_t)s4 * 16 + lane];
    uint4 v5 = f4[(size_t)s5 * 16 + lane];
    uint4 v6 = f4[(size_t)s6 * 16 + lane];
    uint4 v7 = f4[(size_t)s7 * 16 + lane];
    add8(acc, v0); add8(acc, v1); add8(acc, v2); add8(acc, v3);
    add8(acc, v4); add8(acc, v5); add8(acc, v6); add8(acc, v7);
  }
  for (; e + 3 < hi; e += 4){
    int s0 = csr_src[e],     s1 = csr_src[e + 1];
    int s2 = csr_src[e + 2], s3 = csr_src[e + 3];
    uint4 v0 = f4[(size_t)s0 * 16 + lane];
    uint4 v1 = f4[(size_t)s1 * 16 + lane];
    uint4 v2 = f4[(size_t)s2 * 16 + lane];
    uint4 v3 = f4[(size_t)s3 * 16 + lane];
    add8(acc, v0); add8(acc, v1); add8(acc, v2); add8(acc, v3);
  }
  for (; e < hi; ++e){
    uint4 v0 = f4[(size_t)csr_src[e] * 16 + lane];
    add8(acc, v0);
  }
  const float di = deg_inv[node];
  uint4 zv = f4[(size_t)node * 16 + 8 + lane];
  float v[8];
  v[0] = acc[0] * di + bflo(zv.x); v[1] = acc[1] * di + bfhi(zv.x);
  v[2] = acc[2] * di + bflo(zv.y); v[3] = acc[3] * di + bfhi(zv.y);
  v[4] = acc[4] * di + bflo(zv.z); v[5] = acc[5] * di + bfhi(zv.z);
  v[6] = acc[6] * di + bflo(zv.w); v[7] = acc[7] * di + bfhi(zv.w);
  const bool valid = (lane < 5);
  float m = -INFINITY;
  if (valid){
    #pragma unroll
    for (int j = 0; j < 8; j++) m = fmaxf(m, v[j]);
  }
  #pragma unroll
  for (int off = 1; off < 8; off <<= 1) m = fmaxf(m, __shfl_xor(m, off, 64));
  float s = 0.f;
  if (valid){
    #pragma unroll
    for (int j = 0; j < 8; j++) s += __expf(v[j] - m);
  }
  #pragma unroll
  for (int off = 1; off < 8; off <<= 1) s += __shfl_xor(s, off, 64);
  const float ls = m + logf(s);
  if (valid){
    float* op = out + (size_t)node * NCLS + lane * 8;
    *(float4*)op     = make_float4(v[0]-ls, v[1]-ls, v[2]-ls, v[3]-ls);
    *(float4*)(op+4) = make_float4(v[4]-ls, v[5]-ls, v[6]-ls, v[7]-ls);
  }
}

// ---------------- launch ----------------

extern "C" void kernel_launch(void* const* d_in, const int* in_sizes, int n_in,
                              void* d_out, int out_size, void* d_ws, size_t ws_size,
                              hipStream_t stream) {
  const float* x   = (const float*)d_in[0];
  const int*   ei  = (const int*)d_in[1];
  const float* W1l = (const float*)d_in[2];
  const float* b1  = (const float*)d_in[3];
  const float* W1r = (const float*)d_in[4];
  const float* W2l = (const float*)d_in[5];
  const float* b2  = (const float*)d_in[6];
  const float* W2r = (const float*)d_in[7];
  const float* W3l = (const float*)d_in[8];
  const float* b3  = (const float*)d_in[9];
  const float* W3r = (const float*)d_in[10];

  const int N = in_sizes[0] / D;       // 100000
  const int E = in_sizes[1] / 2;       // 1600000
  const int* src = ei;
  const int* dst = ei + E;
  const int nbuk = (N + 127) >> 7;     // 782 buckets of 128 nodes

  char* ws = (char*)d_ws;
  auto alloc = [&](size_t bytes) -> void* {
    void* p = (void*)ws;
    ws += (bytes + 255) & ~(size_t)255;
    return p;
  };
  int*   csr_off  = (int*)  alloc((size_t)(N + 1) * 4);
  float* deg_inv  = (float*)alloc((size_t)N * 4);
  int*   csr_src  = (int*)  alloc((size_t)E * 4);
  u32*   staging  = (u32*)  alloc((size_t)E * 4);
  int*   gcnt     = (int*)  alloc((size_t)NBLK_P1 * nbuk * 4);
  int*   goff     = (int*)  alloc((size_t)NBLK_P1 * nbuk * 4);
  int*   bbase    = (int*)  alloc((size_t)(nbuk + 1) * 4);
  int*   btot     = (int*)  alloc((size_t)(nbuk + 1) * 4);
  u32*   xb       = (u32*)  alloc((size_t)N * D * 2);
  u32*   h2      = (u32*)  alloc((size_t)N * D * 2);   // layer-2 output (no in-place)
  u32*   hbuf     = (u32*)  alloc((size_t)N * D * 2);
  u32*   yz       = (u32*)  alloc((size_t)N * D * 2);
  u32*   Wt1      = (u32*)  alloc((size_t)128 * 128 * 4);
  u32*   Wt2      = (u32*)  alloc((size_t)128 * 128 * 4);
  u32*   Wt3b    = (u32*)  alloc((size_t)128 * 64 * 4);
  float* bias3b   = (float*)alloc((size_t)128 * 4);

  // fused prep: x->bf16, weight converts, partition histogram
  const int n4 = N * D / 4;
  const int nbX = (n4 + 255) / 256;
  prep_k<<<nbX + 160 + NBLK_P1, 256, 0, stream>>>(
      (const float4*)x, (uint2*)xb, n4,
      W1l, W1r, Wt1, W2l, W2r, Wt2,
      W3l, W3r, Wt3b, bias3b, b3,
      dst, gcnt, E, nbuk, nbX);

  // CSR build: parallel bucket scan -> partition -> per-bucket deg+scan+fill
  bsum_k<<<nbuk, 256, 0, stream>>>(gcnt, btot, nbuk);
  scan_k<<<1, 1024, 0, stream>>>(btot, bbase, nbuk);
  goff_k<<<nbuk, 256, 0, stream>>>(gcnt, bbase, goff, nbuk);
  part_fill_k<<<NBLK_P1, 256, 0, stream>>>(src, dst, goff, staging, E, nbuk);
  bucket_csr_k<<<nbuk, 256, 0, stream>>>(staging, bbase, csr_off, deg_inv, csr_src, N);

  const int fblocks = (N + FM - 1) / FM;
  const int gblocks = (N + 127) / 128;
  // layer 1: fused aggregate+GEMM (xb -> hbuf)
  fused_agg_gemm_k<<<fblocks, 256, 0, stream>>>(xb, csr_off, csr_src, deg_inv,
                                                Wt1, b1, hbuf, N);
  // layer 2: fused aggregate+GEMM (hbuf -> h2; separate buffer, gather races in-place)
  fused_agg_gemm_k<<<fblocks, 256, 0, stream>>>(hbuf, csr_off, csr_src, deg_inv,
                                                Wt2, b2, h2, N);
  // layer 3: yz = h2@[W3l|W3r]+b (K=128), then fused mean-gather + log_softmax
  gemm3_mfma_k<<<gblocks, 256, 0, stream>>>(h2, Wt3b, bias3b, yz, N);
  agg_softmax_k<<<(N + 31) / 32, 256, 0, stream>>>(yz, csr_off, csr_src, deg_inv,
                                                   (float*)d_out, N);
}

// Round 5
// 363.207 us; speedup vs baseline: 1.0920x; 1.0920x over previous
//
#include <hip/hip_runtime.h>
#include <math.h>

#define D 128
#define NCLS 40
#define NBLK_P1 256      // partition blocks; bucket = 128 nodes, nbuk <= 1024

typedef unsigned int u32;
typedef __attribute__((ext_vector_type(8))) short short8;
typedef __attribute__((ext_vector_type(4))) float f32x4;

__device__ inline float bflo(u32 u){ return __uint_as_float(u << 16); }
__device__ inline float bfhi(u32 u){ return __uint_as_float(u & 0xffff0000u); }
__device__ inline u32 pack2bf(float a, float b){
  u32 ua = __float_as_uint(a), ub = __float_as_uint(b);
  ua += 0x7fffu + ((ua >> 16) & 1u);
  ub += 0x7fffu + ((ub >> 16) & 1u);
  return (ua >> 16) | (ub & 0xffff0000u);
}
__device__ inline unsigned short pack1bf(float a){
  u32 ua = __float_as_uint(a);
  ua += 0x7fffu + ((ua >> 16) & 1u);
  return (unsigned short)(ua >> 16);
}

// ---------------- fused prep: x->bf16 + weight converts + partition histogram ----------------
// block ranges: [0,nbX) f2bf | 128 Wt1/Wt2 | 32 Wt3b+bias3b | NBLK_P1 hist
__global__ __launch_bounds__(256) void prep_k(
    const float4* __restrict__ x4, uint2* __restrict__ xb, int n4,
    const float* __restrict__ W1l, const float* __restrict__ W1r, u32* __restrict__ Wt1,
    const float* __restrict__ W2l, const float* __restrict__ W2r, u32* __restrict__ Wt2,
    const float* __restrict__ W3l, const float* __restrict__ W3r,
    u32* __restrict__ Wt3b, float* __restrict__ bias3b, const float* __restrict__ b3,
    const int* __restrict__ dst, int* __restrict__ gcnt, int E, int nbuk, int nbX)
{
  __shared__ int cnt[1024];
  const int b = blockIdx.x;
  const int tid = threadIdx.x;
  if (b < nbX){
    int i = b * 256 + tid;
    if (i < n4){
      float4 v = x4[i];
      xb[i] = make_uint2(pack2bf(v.x, v.y), pack2bf(v.z, v.w));
    }
  } else if (b < nbX + 128){
    const bool first = (b < nbX + 64);
    const float* Wl = first ? W1l : W2l;
    const float* Wr = first ? W1r : W2r;
    u32* Wt = first ? Wt1 : Wt2;
    int i = ((b - nbX) & 63) * 256 + tid;         // 0..16383
    int nn = i >> 7, kp = i & 127;
    int k = kp * 2;
    float a, c;
    if (k < 128){ a = Wl[(size_t)k * 128 + nn]; c = Wl[(size_t)(k + 1) * 128 + nn]; }
    else        { a = Wr[(size_t)(k - 128) * 128 + nn]; c = Wr[(size_t)(k - 127) * 128 + nn]; }
    Wt[(size_t)nn * 128 + kp] = pack2bf(a, c);
  } else if (b < nbX + 160){
    // Wt3b[128 out][64 u32 k], K=128: out 0..39 = W3l^T, 64..103 = W3r^T, else 0
    int i = (b - nbX - 128) * 256 + tid;          // 0..8191
    if (i < 128 * 64){
      int nn = i >> 6, kp = i & 63;
      int k = kp * 2;
      float a = 0.f, c = 0.f;
      if (nn < NCLS){
        a = W3l[(size_t)k * NCLS + nn]; c = W3l[(size_t)(k + 1) * NCLS + nn];
      } else if (nn >= 64 && nn < 64 + NCLS){
        int cc = nn - 64;
        a = W3r[(size_t)k * NCLS + cc]; c = W3r[(size_t)(k + 1) * NCLS + cc];
      }
      Wt3b[(size_t)nn * 64 + kp] = pack2bf(a, c);
    }
    if (b == nbX + 128 && tid < 128)
      bias3b[tid] = (tid >= 64 && tid < 64 + NCLS) ? b3[tid - 64] : 0.f;
  } else {
    // partition histogram (LDS only)
    const int hb = b - nbX - 160;                 // 0..NBLK_P1-1
    for (int i = tid; i < nbuk; i += 256) cnt[i] = 0;
    __syncthreads();
    const int per = (E + NBLK_P1 - 1) / NBLK_P1;
    const int e0 = hb * per;
    const int e1 = min(e0 + per, E);
    for (int i = e0 + tid; i < e1; i += 256)
      atomicAdd(&cnt[dst[i] >> 7], 1);
    __syncthreads();
    for (int i = tid; i < nbuk; i += 256)
      gcnt[(size_t)hb * nbuk + i] = cnt[i];
  }
}

// ---------------- CSR build ----------------
// colscan: per-bucket scan over partition blocks -> bucket-relative goff + btot
__global__ __launch_bounds__(256) void colscan_k(
    const int* __restrict__ gcnt, int* __restrict__ goff,
    int* __restrict__ btot, int nbuk)
{
  __shared__ int sm[256];
  const int j = blockIdx.x;
  const int i = threadIdx.x;
  int v = gcnt[(size_t)i * nbuk + j];
  sm[i] = v;
  __syncthreads();
  int acc = v;
  for (int off = 1; off < 256; off <<= 1){
    int t = (i >= off) ? sm[i - off] : 0;
    __syncthreads();
    acc += t; sm[i] = acc;
    __syncthreads();
  }
  goff[(size_t)i * nbuk + j] = acc - v;      // exclusive within bucket
  if (i == 255) btot[j] = acc;
}

__global__ __launch_bounds__(1024) void scan_k(
    const int* __restrict__ btot, int* __restrict__ bbase, int nbuk)
{
  __shared__ int sm[1024];
  const int j = threadIdx.x;
  int v = (j < nbuk) ? btot[j] : 0;
  sm[j] = v;
  __syncthreads();
  int acc = v;
  for (int off = 1; off < 1024; off <<= 1){
    int t = (j >= off) ? sm[j - off] : 0;
    __syncthreads();
    acc += t; sm[j] = acc;
    __syncthreads();
  }
  if (j < nbuk){
    bbase[j] = acc - v;                 // exclusive
    if (j == nbuk - 1) bbase[nbuk] = acc;
  }
}

// P1b: scatter edges into bucket staging; entry = (src<<7)|dst_local (4B; needs src < 2^25)
__global__ __launch_bounds__(256) void part_fill_k(
    const int* __restrict__ src, const int* __restrict__ dst,
    const int* __restrict__ goff, const int* __restrict__ bbase,
    u32* __restrict__ staging, int E, int nbuk)
{
  __shared__ int boff[1024];
  __shared__ int cur[1024];
  const int tid = threadIdx.x;
  for (int i = tid; i < nbuk; i += 256){
    boff[i] = goff[(size_t)blockIdx.x * nbuk + i] + bbase[i];
    cur[i] = 0;
  }
  __syncthreads();
  const int per = (E + NBLK_P1 - 1) / NBLK_P1;
  const int e0 = blockIdx.x * per;
  const int e1 = min(e0 + per, E);
  for (int i = e0 + tid; i < e1; i += 256){
    int d = dst[i];
    int s = src[i];
    int b = d >> 7;
    int p = atomicAdd(&cur[b], 1);
    staging[boff[b] + p] = ((u32)s << 7) | (u32)(d & 127);
  }
}

// P2: one block per bucket. LDS degree histogram -> local scan -> csr_off/deg_inv,
// then ordered csr_src scatter confined to the bucket's ~contiguous window.
__global__ __launch_bounds__(256) void bucket_csr_k(
    const u32* __restrict__ staging, const int* __restrict__ bbase,
    int* __restrict__ csr_off, float* __restrict__ deg_inv,
    int* __restrict__ csr_src, int N)
{
  __shared__ int ldeg[128];
  __shared__ int sm[128];
  __shared__ int lbase[128];
  __shared__ int lpos[128];
  const int b = blockIdx.x;
  const int node0 = b << 7;
  const int tid = threadIdx.x;
  if (tid < 128) ldeg[tid] = 0;
  __syncthreads();
  const int lo = bbase[b], hi = bbase[b + 1];
  for (int i = lo + tid; i < hi; i += 256)
    atomicAdd(&ldeg[staging[i] & 127u], 1);
  __syncthreads();
  if (tid < 128) sm[tid] = ldeg[tid];
  __syncthreads();
  for (int off = 1; off < 128; off <<= 1){
    int t = (tid >= off && tid < 128) ? sm[tid - off] : 0;
    __syncthreads();
    if (tid < 128) sm[tid] += t;
    __syncthreads();
  }
  if (tid < 128){
    const int excl = sm[tid] - ldeg[tid];
    lbase[tid] = lo + excl;
    lpos[tid] = 0;
    const int node = node0 + tid;
    if (node < N){
      csr_off[node] = lo + excl;
      deg_inv[node] = 1.0f / fmaxf((float)ldeg[tid], 1.0f);
    } else if (node == N){
      csr_off[N] = lo + excl;
    }
  }
  if (tid == 0 && b == (int)gridDim.x - 1) csr_off[N] = hi;   // covers N%128==0
  __syncthreads();
  for (int i = lo + tid; i < hi; i += 256){
    u32 v = staging[i];
    int dloc = (int)(v & 127u);
    int p = atomicAdd(&lpos[dloc], 1);
    csr_src[lbase[dloc] + p] = (int)(v >> 7);
  }
}

// ---------------- mean aggregation (bf16 gather via CSR), 8-way unrolled ----------------
__device__ inline void add8(float* acc, uint4 v){
  acc[0] += bflo(v.x); acc[1] += bfhi(v.x);
  acc[2] += bflo(v.y); acc[3] += bfhi(v.y);
  acc[4] += bflo(v.z); acc[5] += bfhi(v.z);
  acc[6] += bflo(v.w); acc[7] += bfhi(v.w);
}

__global__ __launch_bounds__(256) void aggregate_k(
    const u32* __restrict__ feat, const int* __restrict__ coff,
    const int* __restrict__ csr_src, const float* __restrict__ deg_inv,
    u32* __restrict__ agg, int n)
{
  const int g = threadIdx.x >> 4;
  const int lane = threadIdx.x & 15;
  const int node = blockIdx.x * 16 + g;
  if (node >= n) return;
  const int lo = coff[node], hi = coff[node + 1];
  const uint4* __restrict__ f4 = (const uint4*)feat;
  float acc[8] = {0.f,0.f,0.f,0.f,0.f,0.f,0.f,0.f};
  int e = lo;
  for (; e + 7 < hi; e += 8){
    int s0 = csr_src[e],     s1 = csr_src[e + 1];
    int s2 = csr_src[e + 2], s3 = csr_src[e + 3];
    int s4 = csr_src[e + 4], s5 = csr_src[e + 5];
    int s6 = csr_src[e + 6], s7 = csr_src[e + 7];
    uint4 v0 = f4[(size_t)s0 * 16 + lane];
    uint4 v1 = f4[(size_t)s1 * 16 + lane];
    uint4 v2 = f4[(size_t)s2 * 16 + lane];
    uint4 v3 = f4[(size_t)s3 * 16 + lane];
    uint4 v4 = f4[(size_t)s4 * 16 + lane];
    uint4 v5 = f4[(size_t)s5 * 16 + lane];
    uint4 v6 = f4[(size_t)s6 * 16 + lane];
    uint4 v7 = f4[(size_t)s7 * 16 + lane];
    add8(acc, v0); add8(acc, v1); add8(acc, v2); add8(acc, v3);
    add8(acc, v4); add8(acc, v5); add8(acc, v6); add8(acc, v7);
  }
  for (; e + 3 < hi; e += 4){
    int s0 = csr_src[e],     s1 = csr_src[e + 1];
    int s2 = csr_src[e + 2], s3 = csr_src[e + 3];
    uint4 v0 = f4[(size_t)s0 * 16 + lane];
    uint4 v1 = f4[(size_t)s1 * 16 + lane];
    uint4 v2 = f4[(size_t)s2 * 16 + lane];
    uint4 v3 = f4[(size_t)s3 * 16 + lane];
    add8(acc, v0); add8(acc, v1); add8(acc, v2); add8(acc, v3);
  }
  for (; e < hi; ++e){
    uint4 v0 = f4[(size_t)csr_src[e] * 16 + lane];
    add8(acc, v0);
  }
  const float di = deg_inv[node];
  uint4 o;
  o.x = pack2bf(acc[0] * di, acc[1] * di);
  o.y = pack2bf(acc[2] * di, acc[3] * di);
  o.z = pack2bf(acc[4] * di, acc[5] * di);
  o.w = pack2bf(acc[6] * di, acc[7] * di);
  ((uint4*)agg)[(size_t)node * 16 + lane] = o;
}

// ---------------- MFMA dense: out = relu([A1|A2] @ Wt^T + bias), bf16, K=256 ----------------
// Epilogue: pack bf16 into per-wave LDS region, then store coalesced uint4.
__global__ __launch_bounds__(256) void gemm_mfma_k(
    const u32* __restrict__ A1, const u32* __restrict__ A2,
    const u32* __restrict__ Wt, const float* __restrict__ bias,
    u32* __restrict__ out, int n)
{
  __shared__ u32 smem[8704];           // staging: 2*2560 u32; epilogue: 4 waves * 32*136 u16
  u32* As_u = smem;                    // row stride 20 u32 = 40 bf16
  u32* Bs_u = smem + 2560;
  const int tid = threadIdx.x;
  const int row0 = blockIdx.x * 128;
  const int l = tid & 63, w = tid >> 6;
  const int lm = l & 15, lq = l >> 4;

  f32x4 acc[2][8];
  #pragma unroll
  for (int mi = 0; mi < 2; mi++)
    #pragma unroll
    for (int ni = 0; ni < 8; ni++) acc[mi][ni] = (f32x4){0.f, 0.f, 0.f, 0.f};

  for (int kt = 0; kt < 8; ++kt){
    const u32* Ap = (kt < 4) ? A1 : A2;
    const int ko = (kt & 3) * 16;
    #pragma unroll
    for (int i = 0; i < 2; i++){
      int chunk = tid + 256 * i;
      int row = chunk >> 2, q = chunk & 3;
      uint4 av = make_uint4(0, 0, 0, 0);
      int gr = row0 + row;
      if (gr < n) av = *(const uint4*)(Ap + (size_t)gr * 64 + ko + q * 4);
      *(uint4*)&As_u[row * 20 + q * 4] = av;
      uint4 bv = *(const uint4*)(Wt + (size_t)row * 128 + kt * 16 + q * 4);
      *(uint4*)&Bs_u[row * 20 + q * 4] = bv;
    }
    __syncthreads();
    short8 af0 = *(const short8*)&As_u[(w * 32 + lm) * 20 + lq * 4];
    short8 af1 = *(const short8*)&As_u[(w * 32 + 16 + lm) * 20 + lq * 4];
    #pragma unroll
    for (int ni = 0; ni < 8; ni++){
      short8 bf = *(const short8*)&Bs_u[(ni * 16 + lm) * 20 + lq * 4];
      acc[0][ni] = __builtin_amdgcn_mfma_f32_16x16x32_bf16(af0, bf, acc[0][ni], 0, 0, 0);
      acc[1][ni] = __builtin_amdgcn_mfma_f32_16x16x32_bf16(af1, bf, acc[1][ni], 0, 0, 0);
    }
    __syncthreads();
  }

  float bb[8];
  #pragma unroll
  for (int ni = 0; ni < 8; ni++) bb[ni] = bias[ni * 16 + lm];
  unsigned short* es = (unsigned short*)smem + w * (32 * 136);
  #pragma unroll
  for (int mi = 0; mi < 2; mi++)
    #pragma unroll
    for (int r = 0; r < 4; r++){
      const int Lr = mi * 16 + lq * 4 + r;
      #pragma unroll
      for (int ni = 0; ni < 8; ni++){
        float v = fmaxf(acc[mi][ni][r] + bb[ni], 0.f);
        es[Lr * 136 + ni * 16 + lm] = pack1bf(v);
      }
    }
  __syncthreads();
  uint4* outv = (uint4*)out;
  const int cl = l & 15;               // 16 lanes cover a 256B row
  const int rsub = l >> 4;             // 4 rows per pass
  #pragma unroll
  for (int p = 0; p < 8; p++){
    const int Lr = p * 4 + rsub;
    const int row = row0 + w * 32 + Lr;
    uint4 t = *(const uint4*)&es[Lr * 136 + cl * 8];
    if (row < n) outv[(size_t)row * 16 + cl] = t;
  }
}

// ---------------- fused layers 2+3: H = relu([A1|A2]@Wt2^T+b2); yz = H@Wt3b^T+bias3b ----
// H tile (128x128 bf16) stays in LDS between the two MFMA passes -> saves the h2
// round-trip (51MB) and one launch. LDS 45KB -> 3 blocks/CU (streaming, not latency-bound).
__global__ __launch_bounds__(256) void gemm23_mfma_k(
    const u32* __restrict__ A1, const u32* __restrict__ A2,
    const u32* __restrict__ Wt2, const float* __restrict__ b2,
    const u32* __restrict__ Wt3b, const float* __restrict__ bias3b,
    u32* __restrict__ yz, int n)
{
  __shared__ u32 Bs[128 * 20];         // weight staging (both passes)
  __shared__ u32 big[8704];            // As aliases [0,2560); esH = whole as u16[17408]
  u32* As = big;
  unsigned short* esH = (unsigned short*)big;   // 128 rows x 136 u16
  const int tid = threadIdx.x;
  const int row0 = blockIdx.x * 128;
  const int l = tid & 63, w = tid >> 6;
  const int lm = l & 15, lq = l >> 4;

  // ---- pass 1: H = relu([A1|A2] @ Wt2^T + b2), K=256 ----
  f32x4 acc[2][8];
  #pragma unroll
  for (int mi = 0; mi < 2; mi++)
    #pragma unroll
    for (int ni = 0; ni < 8; ni++) acc[mi][ni] = (f32x4){0.f, 0.f, 0.f, 0.f};

  for (int kt = 0; kt < 8; ++kt){
    const u32* Ap = (kt < 4) ? A1 : A2;
    const int ko = (kt & 3) * 16;
    #pragma unroll
    for (int i = 0; i < 2; i++){
      int chunk = tid + 256 * i;
      int row = chunk >> 2, q = chunk & 3;
      uint4 av = make_uint4(0, 0, 0, 0);
      int gr = row0 + row;
      if (gr < n) av = *(const uint4*)(Ap + (size_t)gr * 64 + ko + q * 4);
      *(uint4*)&As[row * 20 + q * 4] = av;
      uint4 bv = *(const uint4*)(Wt2 + (size_t)row * 128 + kt * 16 + q * 4);
      *(uint4*)&Bs[row * 20 + q * 4] = bv;
    }
    __syncthreads();
    short8 af0 = *(const short8*)&As[(w * 32 + lm) * 20 + lq * 4];
    short8 af1 = *(const short8*)&As[(w * 32 + 16 + lm) * 20 + lq * 4];
    #pragma unroll
    for (int ni = 0; ni < 8; ni++){
      short8 bf = *(const short8*)&Bs[(ni * 16 + lm) * 20 + lq * 4];
      acc[0][ni] = __builtin_amdgcn_mfma_f32_16x16x32_bf16(af0, bf, acc[0][ni], 0, 0, 0);
      acc[1][ni] = __builtin_amdgcn_mfma_f32_16x16x32_bf16(af1, bf, acc[1][ni], 0, 0, 0);
    }
    __syncthreads();
  }

  // epilogue 1: H -> esH (bf16, row stride 136 u16; global row indexing)
  {
    float bb[8];
    #pragma unroll
    for (int ni = 0; ni < 8; ni++) bb[ni] = b2[ni * 16 + lm];
    #pragma unroll
    for (int mi = 0; mi < 2; mi++)
      #pragma unroll
      for (int r = 0; r < 4; r++){
        const int grow = w * 32 + mi * 16 + lq * 4 + r;
        #pragma unroll
        for (int ni = 0; ni < 8; ni++){
          float v = fmaxf(acc[mi][ni][r] + bb[ni], 0.f);
          esH[grow * 136 + ni * 16 + lm] = pack1bf(v);
        }
      }
  }
  __syncthreads();

  // ---- pass 2: yz = H @ Wt3b^T + bias3b, K=128 (A from esH) ----
  f32x4 acc2[2][8];
  #pragma unroll
  for (int mi = 0; mi < 2; mi++)
    #pragma unroll
    for (int ni = 0; ni < 8; ni++) acc2[mi][ni] = (f32x4){0.f, 0.f, 0.f, 0.f};

  for (int kt = 0; kt < 4; ++kt){
    #pragma unroll
    for (int i = 0; i < 2; i++){
      int c2 = tid + 256 * i;
      int brow = c2 >> 2, q = c2 & 3;
      uint4 bv = *(const uint4*)(Wt3b + (size_t)brow * 64 + kt * 16 + q * 4);
      *(uint4*)&Bs[brow * 20 + q * 4] = bv;
    }
    __syncthreads();
    short8 a0 = *(const short8*)&esH[(w * 32 + lm) * 136 + kt * 32 + lq * 8];
    short8 a1 = *(const short8*)&esH[(w * 32 + 16 + lm) * 136 + kt * 32 + lq * 8];
    #pragma unroll
    for (int ni = 0; ni < 8; ni++){
      short8 bf = *(const short8*)&Bs[(ni * 16 + lm) * 20 + lq * 4];
      acc2[0][ni] = __builtin_amdgcn_mfma_f32_16x16x32_bf16(a0, bf, acc2[0][ni], 0, 0, 0);
      acc2[1][ni] = __builtin_amdgcn_mfma_f32_16x16x32_bf16(a1, bf, acc2[1][ni], 0, 0, 0);
    }
    __syncthreads();
  }

  // epilogue 2: yz -> esH (overwrite; all reads done), then coalesced store
  {
    float bb3[8];
    #pragma unroll
    for (int ni = 0; ni < 8; ni++) bb3[ni] = bias3b[ni * 16 + lm];
    #pragma unroll
    for (int mi = 0; mi < 2; mi++)
      #pragma unroll
      for (int r = 0; r < 4; r++){
        const int grow = w * 32 + mi * 16 + lq * 4 + r;
        #pragma unroll
        for (int ni = 0; ni < 8; ni++){
          float v = acc2[mi][ni][r] + bb3[ni];
          esH[grow * 136 + ni * 16 + lm] = pack1bf(v);
        }
      }
  }
  __syncthreads();
  uint4* outv = (uint4*)yz;
  const int cl = l & 15;
  const int rsub = l >> 4;
  #pragma unroll
  for (int p = 0; p < 8; p++){
    const int Lr = p * 4 + rsub;
    const int row = row0 + w * 32 + Lr;
    uint4 t = *(const uint4*)&esH[(w * 32 + Lr) * 136 + cl * 8];
    if (row < n) outv[(size_t)row * 16 + cl] = t;
  }
}

// ---------------- fused: out = log_softmax(mean-gather(y) + z), 8-way unrolled ----------------
__global__ __launch_bounds__(256) void agg_softmax_k(
    const u32* __restrict__ yz, const int* __restrict__ coff,
    const int* __restrict__ csr_src, const float* __restrict__ deg_inv,
    float* __restrict__ out, int n)
{
  const int g = threadIdx.x >> 3;
  const int lane = threadIdx.x & 7;
  const int node = blockIdx.x * 32 + g;
  if (node >= n) return;
  const int lo = coff[node], hi = coff[node + 1];
  const uint4* __restrict__ f4 = (const uint4*)yz;    // 16 uint4 per row; y = first 8
  float acc[8] = {0.f,0.f,0.f,0.f,0.f,0.f,0.f,0.f};
  int e = lo;
  for (; e + 7 < hi; e += 8){
    int s0 = csr_src[e],     s1 = csr_src[e + 1];
    int s2 = csr_src[e + 2], s3 = csr_src[e + 3];
    int s4 = csr_src[e + 4], s5 = csr_src[e + 5];
    int s6 = csr_src[e + 6], s7 = csr_src[e + 7];
    uint4 v0 = f4[(size_t)s0 * 16 + lane];
    uint4 v1 = f4[(size_t)s1 * 16 + lane];
    uint4 v2 = f4[(size_t)s2 * 16 + lane];
    uint4 v3 = f4[(size_t)s3 * 16 + lane];
    uint4 v4 = f4[(size_t)s4 * 16 + lane];
    uint4 v5 = f4[(size_t)s5 * 16 + lane];
    uint4 v6 = f4[(size_t)s6 * 16 + lane];
    uint4 v7 = f4[(size_t)s7 * 16 + lane];
    add8(acc, v0); add8(acc, v1); add8(acc, v2); add8(acc, v3);
    add8(acc, v4); add8(acc, v5); add8(acc, v6); add8(acc, v7);
  }
  for (; e + 3 < hi; e += 4){
    int s0 = csr_src[e],     s1 = csr_src[e + 1];
    int s2 = csr_src[e + 2], s3 = csr_src[e + 3];
    uint4 v0 = f4[(size_t)s0 * 16 + lane];
    uint4 v1 = f4[(size_t)s1 * 16 + lane];
    uint4 v2 = f4[(size_t)s2 * 16 + lane];
    uint4 v3 = f4[(size_t)s3 * 16 + lane];
    add8(acc, v0); add8(acc, v1); add8(acc, v2); add8(acc, v3);
  }
  for (; e < hi; ++e){
    uint4 v0 = f4[(size_t)csr_src[e] * 16 + lane];
    add8(acc, v0);
  }
  const float di = deg_inv[node];
  uint4 zv = f4[(size_t)node * 16 + 8 + lane];
  float v[8];
  v[0] = acc[0] * di + bflo(zv.x); v[1] = acc[1] * di + bfhi(zv.x);
  v[2] = acc[2] * di + bflo(zv.y); v[3] = acc[3] * di + bfhi(zv.y);
  v[4] = acc[4] * di + bflo(zv.z); v[5] = acc[5] * di + bfhi(zv.z);
  v[6] = acc[6] * di + bflo(zv.w); v[7] = acc[7] * di + bfhi(zv.w);
  const bool valid = (lane < 5);
  float m = -INFINITY;
  if (valid){
    #pragma unroll
    for (int j = 0; j < 8; j++) m = fmaxf(m, v[j]);
  }
  #pragma unroll
  for (int off = 1; off < 8; off <<= 1) m = fmaxf(m, __shfl_xor(m, off, 64));
  float s = 0.f;
  if (valid){
    #pragma unroll
    for (int j = 0; j < 8; j++) s += __expf(v[j] - m);
  }
  #pragma unroll
  for (int off = 1; off < 8; off <<= 1) s += __shfl_xor(s, off, 64);
  const float ls = m + logf(s);
  if (valid){
    float* op = out + (size_t)node * NCLS + lane * 8;
    *(float4*)op     = make_float4(v[0]-ls, v[1]-ls, v[2]-ls, v[3]-ls);
    *(float4*)(op+4) = make_float4(v[4]-ls, v[5]-ls, v[6]-ls, v[7]-ls);
  }
}

// ---------------- launch ----------------

extern "C" void kernel_launch(void* const* d_in, const int* in_sizes, int n_in,
                              void* d_out, int out_size, void* d_ws, size_t ws_size,
                              hipStream_t stream) {
  const float* x   = (const float*)d_in[0];
  const int*   ei  = (const int*)d_in[1];
  const float* W1l = (const float*)d_in[2];
  const float* b1  = (const float*)d_in[3];
  const float* W1r = (const float*)d_in[4];
  const float* W2l = (const float*)d_in[5];
  const float* b2  = (const float*)d_in[6];
  const float* W2r = (const float*)d_in[7];
  const float* W3l = (const float*)d_in[8];
  const float* b3  = (const float*)d_in[9];
  const float* W3r = (const float*)d_in[10];

  const int N = in_sizes[0] / D;       // 100000
  const int E = in_sizes[1] / 2;       // 1600000
  const int* src = ei;
  const int* dst = ei + E;
  const int nbuk = (N + 127) >> 7;     // 782 buckets of 128 nodes

  char* ws = (char*)d_ws;
  auto alloc = [&](size_t bytes) -> void* {
    void* p = (void*)ws;
    ws += (bytes + 255) & ~(size_t)255;
    return p;
  };
  int*   csr_off  = (int*)  alloc((size_t)(N + 1) * 4);
  float* deg_inv  = (float*)alloc((size_t)N * 4);
  int*   csr_src  = (int*)  alloc((size_t)E * 4);
  u32*   staging  = (u32*)  alloc((size_t)E * 4);
  int*   gcnt     = (int*)  alloc((size_t)NBLK_P1 * nbuk * 4);
  int*   goff     = (int*)  alloc((size_t)NBLK_P1 * nbuk * 4);
  int*   bbase    = (int*)  alloc((size_t)(nbuk + 1) * 4);
  int*   btot     = (int*)  alloc((size_t)(nbuk + 1) * 4);
  u32*   xb       = (u32*)  alloc((size_t)N * D * 2);
  u32*   agg      = (u32*)  alloc((size_t)N * D * 2);
  u32*   hbuf     = (u32*)  alloc((size_t)N * D * 2);
  u32*   yz       = (u32*)  alloc((size_t)N * D * 2);
  u32*   Wt1      = (u32*)  alloc((size_t)128 * 128 * 4);
  u32*   Wt2      = (u32*)  alloc((size_t)128 * 128 * 4);
  u32*   Wt3b     = (u32*)  alloc((size_t)128 * 64 * 4);
  float* bias3b   = (float*)alloc((size_t)128 * 4);

  // fused prep: x->bf16, weight converts, partition histogram
  const int n4 = N * D / 4;
  const int nbX = (n4 + 255) / 256;
  prep_k<<<nbX + 160 + NBLK_P1, 256, 0, stream>>>(
      (const float4*)x, (uint2*)xb, n4,
      W1l, W1r, Wt1, W2l, W2r, Wt2,
      W3l, W3r, Wt3b, bias3b, b3,
      dst, gcnt, E, nbuk, nbX);

  // CSR build: colscan -> bucket scan -> partition -> per-bucket deg+scan+fill
  colscan_k<<<nbuk, 256, 0, stream>>>(gcnt, goff, btot, nbuk);
  scan_k<<<1, 1024, 0, stream>>>(btot, bbase, nbuk);
  part_fill_k<<<NBLK_P1, 256, 0, stream>>>(src, dst, goff, bbase, staging, E, nbuk);
  bucket_csr_k<<<nbuk, 256, 0, stream>>>(staging, bbase, csr_off, deg_inv, csr_src, N);

  const int gblocks = (N + 127) / 128;
  const int ablocks = (N + 15) / 16;
  // layer 1
  aggregate_k<<<ablocks, 256, 0, stream>>>(xb, csr_off, csr_src, deg_inv, agg, N);
  gemm_mfma_k<<<gblocks, 256, 0, stream>>>(agg, xb, Wt1, b1, hbuf, N);
  // layer 2 aggregate, then fused layer-2 GEMM + layer-3 GEMM -> yz
  aggregate_k<<<ablocks, 256, 0, stream>>>(hbuf, csr_off, csr_src, deg_inv, agg, N);
  gemm23_mfma_k<<<gblocks, 256, 0, stream>>>(agg, hbuf, Wt2, b2, Wt3b, bias3b, yz, N);
  // layer 3: fused mean-gather + log_softmax
  agg_softmax_k<<<(N + 31) / 32, 256, 0, stream>>>(yz, csr_off, csr_src, deg_inv,
                                                   (float*)d_out, N);
}